// Round 12
// baseline (355.194 us; speedup 1.0000x reference)
//
#include <hip/hip_runtime.h>
#include <cstdint>
#include <cstddef>
#include <cmath>

#define NN   100000   // nodes per graph
#define NE   1600000  // edges per graph
#define DD   64       // feature dim
#define NG   4        // graphs
#define NB_  32       // batch
#define NL   50       // candidate list length
#define NCL  2        // attention layers per stack
#define SCAN_NB 49    // ceil(NN/2048)
#define STRIDE 80     // edge slots per marked row (Poisson(16): P(deg>80)~1e-34; exact fallback exists)
#define ROWCAP 32768  // max marked rows stored per graph (actual ~27k)
#define WPAD 68

// ---------------------------------------------------------------- transpose layer-1 weights (per graph): wt[gy] = [WsT | WnT]
__global__ __launch_bounds__(256) void k_wt(const float* __restrict__ Ws,
                                            const float* __restrict__ Wn,
                                            float* __restrict__ wt, int g0) {
    const int gy = blockIdx.y;
    const int g = g0 + gy;
    float* o = wt + (size_t)gy * 2 * DD * DD;
    int i = blockIdx.x * 256 + threadIdx.x;
    if (i < DD * DD) {
        int r = i >> 6, k = i & 63;
        o[k * DD + r] = Ws[(size_t)g * DD * DD + r * DD + k];
        o[DD * DD + k * DD + r] = Wn[(size_t)g * DD * DD + r * DD + k];
    }
}

// ---------------------------------------------------------------- mark candidates
__global__ __launch_bounds__(256) void k_candmark(const int* __restrict__ cand,
                                                  int* __restrict__ candbm,
                                                  int* __restrict__ mark, int g0) {
    const int gy = blockIdx.y;
    const int g = g0 + gy;
    int t = blockIdx.x * 256 + threadIdx.x;
    if (t < NB_ * NL) {
        int b = t / NL, l = t - b * NL;
        int n = cand[((size_t)b * NG + g) * NL + l];
        candbm[(size_t)gy * NN + n] = 1;
        mark[(size_t)gy * NN + n] = 1;
    }
}

// stream edges: mark sources feeding candidates
__global__ __launch_bounds__(256) void k_mark2(const int* __restrict__ src,
                                               const int* __restrict__ dst,
                                               const int* __restrict__ candbm,
                                               int* __restrict__ mark, int g0) {
    const int gy = blockIdx.y;
    const int g = g0 + gy;
    int q = blockIdx.x * 256 + threadIdx.x;
    if (q < NE / 4) {
        int4 dv = ((const int4*)(dst + (size_t)g * NE))[q];
        int4 sv = ((const int4*)(src + (size_t)g * NE))[q];
        const int* cb = candbm + (size_t)gy * NN;
        int* mk = mark + (size_t)gy * NN;
        if (cb[dv.x]) mk[sv.x] = 1;
        if (cb[dv.y]) mk[sv.y] = 1;
        if (cb[dv.z]) mk[sv.z] = 1;
        if (cb[dv.w]) mk[sv.w] = 1;
    }
}

// ---------------------------------------------------------------- compact marked -> list + rank
__global__ __launch_bounds__(256) void k_cscan1(const int* __restrict__ mark,
                                                int* __restrict__ partc) {
    const int gy = blockIdx.y;
    const int* m = mark + (size_t)gy * NN;
    __shared__ int sh[256];
    const int tid = threadIdx.x;
    int base = blockIdx.x * 2048 + tid * 8;
    int s = 0;
    for (int i = 0; i < 8; ++i) { int idx = base + i; if (idx < NN) s += m[idx]; }
    sh[tid] = s; __syncthreads();
    for (int off = 128; off > 0; off >>= 1) {
        if (tid < off) sh[tid] += sh[tid + off];
        __syncthreads();
    }
    if (tid == 0) partc[gy * 64 + blockIdx.x] = sh[0];
}

__global__ __launch_bounds__(256) void k_cscan3(const int* __restrict__ mark,
                                                const int* __restrict__ partc,
                                                int* __restrict__ list,
                                                int* __restrict__ rank,
                                                int* __restrict__ nlist) {
    const int gy = blockIdx.y;
    const int* m = mark + (size_t)gy * NN;
    int* li = list + (size_t)gy * NN;
    int* rk = rank + (size_t)gy * NN;
    __shared__ int sh[256];
    __shared__ int sbase;
    const int tid = threadIdx.x;
    if (tid == 0) {
        int b = 0;
        for (int i = 0; i < blockIdx.x; ++i) b += partc[gy * 64 + i];
        sbase = b;
    }
    int base = blockIdx.x * 2048 + tid * 8;
    int vals[8];
    int s = 0;
    for (int i = 0; i < 8; ++i) {
        int idx = base + i;
        int v = (idx < NN) ? m[idx] : 0;
        vals[i] = v; s += v;
    }
    sh[tid] = s; __syncthreads();
    for (int off = 1; off < 256; off <<= 1) {
        int t = (tid >= off) ? sh[tid - off] : 0;
        __syncthreads();
        sh[tid] += t;
        __syncthreads();
    }
    int excl = sh[tid] - s;
    int run = sbase + excl;
    for (int i = 0; i < 8; ++i) {
        int idx = base + i;
        if (idx < NN) {
            if (vals[i]) { li[run] = idx; rk[idx] = run + 1; ++run; }
            else rk[idx] = 0;
        }
    }
    if (blockIdx.x == SCAN_NB - 1 && tid == 255) nlist[gy] = sbase + sh[255];
}

// ---------------------------------------------------------------- fixed-stride scatter: slot base = rank*STRIDE, atomic cursor per row
__global__ __launch_bounds__(256) void k_scatter3(const int* __restrict__ src,
                                                  const int* __restrict__ dst,
                                                  const float* __restrict__ ew,
                                                  const int* __restrict__ rank,
                                                  int* __restrict__ cur,
                                                  int2* __restrict__ edf, int g0) {
    const int gy = blockIdx.y;
    const int g = g0 + gy;
    int q = blockIdx.x * 256 + threadIdx.x;
    if (q < NE / 4) {
        int4   dv = ((const int4*)(dst + (size_t)g * NE))[q];
        int4   sv = ((const int4*)(src + (size_t)g * NE))[q];
        float4 wv = ((const float4*)(ew + (size_t)g * NE))[q];
        const int* rk = rank + (size_t)gy * NN;
        int* cu = cur + (size_t)gy * ROWCAP;
        int2* ef = edf + (size_t)gy * ROWCAP * STRIDE;
        int r0 = rk[dv.x] - 1;
        if (r0 >= 0 && r0 < ROWCAP) { int p = atomicAdd(&cu[r0], 1); if (p < STRIDE) ef[(size_t)r0 * STRIDE + p] = make_int2(sv.x, __float_as_int(wv.x)); }
        int r1 = rk[dv.y] - 1;
        if (r1 >= 0 && r1 < ROWCAP) { int p = atomicAdd(&cu[r1], 1); if (p < STRIDE) ef[(size_t)r1 * STRIDE + p] = make_int2(sv.y, __float_as_int(wv.y)); }
        int r2 = rk[dv.z] - 1;
        if (r2 >= 0 && r2 < ROWCAP) { int p = atomicAdd(&cu[r2], 1); if (p < STRIDE) ef[(size_t)r2 * STRIDE + p] = make_int2(sv.z, __float_as_int(wv.z)); }
        int r3 = rk[dv.w] - 1;
        if (r3 >= 0 && r3 < ROWCAP) { int p = atomicAdd(&cu[r3], 1); if (p < STRIDE) ef[(size_t)r3 * STRIDE + p] = make_int2(sv.w, __float_as_int(wv.w)); }
    }
}

// ---------------------------------------------------------------- raw-stream exact fallback for deg > STRIDE (effectively never)
__device__ __forceinline__ float conv_raw_fallback(const int* __restrict__ rawsrc,
                                                   const int* __restrict__ rawdst,
                                                   const float* __restrict__ rawew,
                                                   const float* __restrict__ feat,
                                                   int g, int n, int lane) {
    float acc = 0.f;
    for (int base = 0; base < NE; base += 64) {
        int d = rawdst[(size_t)g * NE + base + lane];
        int s = rawsrc[(size_t)g * NE + base + lane];
        float w = rawew[(size_t)g * NE + base + lane];
        unsigned long long mball = __ballot(d == n);
        while (mball) {
            int i = __ffsll(mball) - 1; mball &= mball - 1;
            acc = fmaf(feat[(size_t)__shfl(s, i) * DD + lane], __shfl(w, i), acc);
        }
    }
    return acc;
}

// ---------------------------------------------------------------- fused SAGE conv (layer 1, relu): TILE=4, pairwise-interleaved gathers
// Rows (0,1) and (2,3) gather in lockstep with separate register sets ->
// 16 feature loads in flight, cross-row serial chain halved. All acc/rec
// indexing static (no scratch). LDS 8KB/block.
__global__ __launch_bounds__(256) void k_conv_full(
    const float* __restrict__ emb, const int2* __restrict__ edf,
    const int* __restrict__ cur, const float* __restrict__ wt,
    const float* __restrict__ bias, float* __restrict__ outh,
    const int* __restrict__ list, const int* __restrict__ nlist,
    const int* __restrict__ rawsrc, const int* __restrict__ rawdst,
    const float* __restrict__ rawew, int g0)
{
    const int gy = blockIdx.y;
    const int g = g0 + gy;
    const float* feat = emb + (size_t)g * NN * DD;
    const int2* ed = edf + (size_t)gy * ROWCAP * STRIDE;
    const int* cu = cur + (size_t)gy * ROWCAP;
    const int* li = list + (size_t)gy * NN;
    const float* wsT = wt + (size_t)gy * 2 * DD * DD;
    const float* wnT = wsT + DD * DD;
    float* og = outh + (size_t)gy * ROWCAP * DD;
    const int lane = threadIdx.x & 63;
    const int wid = threadIdx.x >> 6;

    __shared__ __attribute__((aligned(16))) float fs[4][4][DD];
    __shared__ __attribute__((aligned(16))) float ns[4][4][DD];

    const float bv = bias[(size_t)g * DD + lane];
    const int nl = min(nlist[gy], ROWCAP);
    const int wglob = blockIdx.x * 4 + wid;
    const int wstep = gridDim.x * 4;
    for (int tb = wglob * 4; tb < nl; tb += wstep * 4) {
        const int nrows = min(4, nl - tb);
        int nL = 0, cL = 0;
        if (lane < nrows) { nL = li[tb + lane]; cL = cu[tb + lane]; }
        // prefetch records + self rows (8 independent loads in flight)
        int2 rec0 = make_int2(0, 0), rec1 = make_int2(0, 0);
        int2 rec2 = make_int2(0, 0), rec3 = make_int2(0, 0);
        {
            int c0 = min(__shfl(cL, 0), 64);
            if (lane < c0) rec0 = ed[(size_t)(tb + 0) * STRIDE + lane];
            if (nrows > 1) { int c = min(__shfl(cL, 1), 64); if (lane < c) rec1 = ed[(size_t)(tb + 1) * STRIDE + lane]; }
            if (nrows > 2) { int c = min(__shfl(cL, 2), 64); if (lane < c) rec2 = ed[(size_t)(tb + 2) * STRIDE + lane]; }
            if (nrows > 3) { int c = min(__shfl(cL, 3), 64); if (lane < c) rec3 = ed[(size_t)(tb + 3) * STRIDE + lane]; }
        }
        fs[wid][0][lane] = feat[(size_t)__shfl(nL, 0) * DD + lane];
        if (nrows > 1) fs[wid][1][lane] = feat[(size_t)__shfl(nL, 1) * DD + lane];
        if (nrows > 2) fs[wid][2][lane] = feat[(size_t)__shfl(nL, 2) * DD + lane];
        if (nrows > 3) fs[wid][3][lane] = feat[(size_t)__shfl(nL, 3) * DD + lane];

        float acc0 = 0.f, acc1 = 0.f, acc2 = 0.f, acc3 = 0.f;
        // ---- pair (0,1): interleaved gather groups (16 loads in flight)
        {
            const int cA = min(__shfl(cL, 0), 64);
            const int cB = (nrows > 1) ? min(__shfl(cL, 1), 64) : 0;
            const int sA = rec0.x; const float wA = __int_as_float(rec0.y);
            const int sB = rec1.x; const float wB = __int_as_float(rec1.y);
            const int lim = max(cA, cB);
            for (int j = 0; j < lim; j += 8) {
                float fvA[8], fvB[8];
                const bool doA = j < cA, doB = j < cB;
                if (doA) {
#pragma unroll
                    for (int u = 0; u < 8; ++u) fvA[u] = feat[(size_t)__shfl(sA, j + u) * DD + lane];
                }
                if (doB) {
#pragma unroll
                    for (int u = 0; u < 8; ++u) fvB[u] = feat[(size_t)__shfl(sB, j + u) * DD + lane];
                }
                if (doA) {
#pragma unroll
                    for (int u = 0; u < 8; ++u) acc0 = fmaf(fvA[u], __shfl(wA, j + u), acc0);
                }
                if (doB) {
#pragma unroll
                    for (int u = 0; u < 8; ++u) acc1 = fmaf(fvB[u], __shfl(wB, j + u), acc1);
                }
            }
        }
        // ---- pair (2,3)
        if (nrows > 2) {
            const int cA = min(__shfl(cL, 2), 64);
            const int cB = (nrows > 3) ? min(__shfl(cL, 3), 64) : 0;
            const int sA = rec2.x; const float wA = __int_as_float(rec2.y);
            const int sB = rec3.x; const float wB = __int_as_float(rec3.y);
            const int lim = max(cA, cB);
            for (int j = 0; j < lim; j += 8) {
                float fvA[8], fvB[8];
                const bool doA = j < cA, doB = j < cB;
                if (doA) {
#pragma unroll
                    for (int u = 0; u < 8; ++u) fvA[u] = feat[(size_t)__shfl(sA, j + u) * DD + lane];
                }
                if (doB) {
#pragma unroll
                    for (int u = 0; u < 8; ++u) fvB[u] = feat[(size_t)__shfl(sB, j + u) * DD + lane];
                }
                if (doA) {
#pragma unroll
                    for (int u = 0; u < 8; ++u) acc2 = fmaf(fvA[u], __shfl(wA, j + u), acc2);
                }
                if (doB) {
#pragma unroll
                    for (int u = 0; u < 8; ++u) acc3 = fmaf(fvB[u], __shfl(wB, j + u), acc3);
                }
            }
        }
        // ---- tails (deg 65..STRIDE cold; deg>STRIDE exact raw fallback) + ns writes
        {
            const int cnt = __shfl(cL, 0);
            if (cnt > 64) {
                if (cnt <= STRIDE) {
                    for (int j = 64; j < cnt; ++j) {
                        int2 e = ed[(size_t)(tb + 0) * STRIDE + j];
                        acc0 = fmaf(feat[(size_t)e.x * DD + lane], __int_as_float(e.y), acc0);
                    }
                } else acc0 = conv_raw_fallback(rawsrc, rawdst, rawew, feat, g, __shfl(nL, 0), lane);
            }
            ns[wid][0][lane] = acc0 / fmaxf((float)cnt, 1.f);
        }
        if (nrows > 1) {
            const int cnt = __shfl(cL, 1);
            if (cnt > 64) {
                if (cnt <= STRIDE) {
                    for (int j = 64; j < cnt; ++j) {
                        int2 e = ed[(size_t)(tb + 1) * STRIDE + j];
                        acc1 = fmaf(feat[(size_t)e.x * DD + lane], __int_as_float(e.y), acc1);
                    }
                } else acc1 = conv_raw_fallback(rawsrc, rawdst, rawew, feat, g, __shfl(nL, 1), lane);
            }
            ns[wid][1][lane] = acc1 / fmaxf((float)cnt, 1.f);
        }
        if (nrows > 2) {
            const int cnt = __shfl(cL, 2);
            if (cnt > 64) {
                if (cnt <= STRIDE) {
                    for (int j = 64; j < cnt; ++j) {
                        int2 e = ed[(size_t)(tb + 2) * STRIDE + j];
                        acc2 = fmaf(feat[(size_t)e.x * DD + lane], __int_as_float(e.y), acc2);
                    }
                } else acc2 = conv_raw_fallback(rawsrc, rawdst, rawew, feat, g, __shfl(nL, 2), lane);
            }
            ns[wid][2][lane] = acc2 / fmaxf((float)cnt, 1.f);
        }
        if (nrows > 3) {
            const int cnt = __shfl(cL, 3);
            if (cnt > 64) {
                if (cnt <= STRIDE) {
                    for (int j = 64; j < cnt; ++j) {
                        int2 e = ed[(size_t)(tb + 3) * STRIDE + j];
                        acc3 = fmaf(feat[(size_t)e.x * DD + lane], __int_as_float(e.y), acc3);
                    }
                } else acc3 = conv_raw_fallback(rawsrc, rawdst, rawew, feat, g, __shfl(nL, 3), lane);
            }
            ns[wid][3][lane] = acc3 / fmaxf((float)cnt, 1.f);
        }
        // ---- phase 2: register-blocked matvec (4 rows, all-static indexing)
        float o0 = bv, o1 = bv, o2 = bv, o3 = bv;
        for (int k4 = 0; k4 < 16; ++k4) {
            float ws0 = wsT[(4 * k4 + 0) * DD + lane];
            float ws1 = wsT[(4 * k4 + 1) * DD + lane];
            float ws2 = wsT[(4 * k4 + 2) * DD + lane];
            float ws3 = wsT[(4 * k4 + 3) * DD + lane];
            float wn0 = wnT[(4 * k4 + 0) * DD + lane];
            float wn1 = wnT[(4 * k4 + 1) * DD + lane];
            float wn2 = wnT[(4 * k4 + 2) * DD + lane];
            float wn3 = wnT[(4 * k4 + 3) * DD + lane];
            float4 f, nv;
            f = *(const float4*)&fs[wid][0][4 * k4]; nv = *(const float4*)&ns[wid][0][4 * k4];
            o0 = fmaf(ws0, f.x, o0); o0 = fmaf(ws1, f.y, o0); o0 = fmaf(ws2, f.z, o0); o0 = fmaf(ws3, f.w, o0);
            o0 = fmaf(wn0, nv.x, o0); o0 = fmaf(wn1, nv.y, o0); o0 = fmaf(wn2, nv.z, o0); o0 = fmaf(wn3, nv.w, o0);
            f = *(const float4*)&fs[wid][1][4 * k4]; nv = *(const float4*)&ns[wid][1][4 * k4];
            o1 = fmaf(ws0, f.x, o1); o1 = fmaf(ws1, f.y, o1); o1 = fmaf(ws2, f.z, o1); o1 = fmaf(ws3, f.w, o1);
            o1 = fmaf(wn0, nv.x, o1); o1 = fmaf(wn1, nv.y, o1); o1 = fmaf(wn2, nv.z, o1); o1 = fmaf(wn3, nv.w, o1);
            f = *(const float4*)&fs[wid][2][4 * k4]; nv = *(const float4*)&ns[wid][2][4 * k4];
            o2 = fmaf(ws0, f.x, o2); o2 = fmaf(ws1, f.y, o2); o2 = fmaf(ws2, f.z, o2); o2 = fmaf(ws3, f.w, o2);
            o2 = fmaf(wn0, nv.x, o2); o2 = fmaf(wn1, nv.y, o2); o2 = fmaf(wn2, nv.z, o2); o2 = fmaf(wn3, nv.w, o2);
            f = *(const float4*)&fs[wid][3][4 * k4]; nv = *(const float4*)&ns[wid][3][4 * k4];
            o3 = fmaf(ws0, f.x, o3); o3 = fmaf(ws1, f.y, o3); o3 = fmaf(ws2, f.z, o3); o3 = fmaf(ws3, f.w, o3);
            o3 = fmaf(wn0, nv.x, o3); o3 = fmaf(wn1, nv.y, o3); o3 = fmaf(wn2, nv.z, o3); o3 = fmaf(wn3, nv.w, o3);
        }
        og[(size_t)(tb + 0) * DD + lane] = fmaxf(o0, 0.f);
        if (nrows > 1) og[(size_t)(tb + 1) * DD + lane] = fmaxf(o1, 0.f);
        if (nrows > 2) og[(size_t)(tb + 2) * DD + lane] = fmaxf(o2, 0.f);
        if (nrows > 3) og[(size_t)(tb + 3) * DD + lane] = fmaxf(o3, 0.f);
    }
}

// ---------------------------------------------------------------- fused SAGE conv at candidates (layer 2), h indexed via rank
__global__ __launch_bounds__(256) void k_conv_cand(
    const float* __restrict__ hfeat, const int2* __restrict__ edf,
    const int* __restrict__ cur, const int* __restrict__ rank,
    const float* __restrict__ Wsf, const float* __restrict__ Wng,
    const float* __restrict__ bias, const int* __restrict__ cand,
    const int* __restrict__ rawsrc, const int* __restrict__ rawdst,
    const float* __restrict__ rawew,
    float* __restrict__ sel, int g0)
{
    const int gy = blockIdx.y;
    const int g = g0 + gy;
    const float* feat = hfeat + (size_t)gy * ROWCAP * DD;  // rank-indexed
    const int2* ed = edf + (size_t)gy * ROWCAP * STRIDE;
    const int* cu = cur + (size_t)gy * ROWCAP;
    const int* rk = rank + (size_t)gy * NN;
    const int lane = threadIdx.x & 63;
    const int wid = threadIdx.x >> 6;

    __shared__ __attribute__((aligned(16))) float lws[DD][WPAD];
    __shared__ __attribute__((aligned(16))) float lwn[DD][WPAD];
    __shared__ __attribute__((aligned(16))) float fs[4][DD];
    __shared__ __attribute__((aligned(16))) float nsh[4][DD];

    for (int i = threadIdx.x; i < DD * 16; i += 256) {
        int row = i >> 4, blk = i & 15;
        *(float4*)&lws[row][blk * 4] = *(const float4*)(Wsf + (size_t)g * DD * DD + (size_t)row * DD + blk * 4);
        *(float4*)&lwn[row][blk * 4] = *(const float4*)(Wng + (size_t)g * DD * DD + (size_t)row * DD + blk * 4);
    }
    __syncthreads();
    const float bv = bias[(size_t)g * DD + lane];

    int t = blockIdx.x * 4 + wid;  // 0..1599
    if (t < NB_ * NL) {
        int b = t / NL;
        int l = t - b * NL;
        int n = cand[((size_t)b * NG + g) * NL + l];
        const int rc = rk[n] - 1;             // candidate is marked
        const int cnt = cu[rc];
        const float fself = feat[(size_t)rc * DD + lane];
        float acc = 0.f;
        if (cnt <= STRIDE) {
            const int c64 = min(cnt, 64);
            int myS = 0; float myW = 0.f;
            if (lane < c64) {
                int2 e = ed[(size_t)rc * STRIDE + lane];
                myS = rk[e.x] - 1;            // sources of candidates are marked
                myW = __int_as_float(e.y);
            }
            for (int j = 0; j < c64; j += 8) {
                float fv[8], wv[8];
#pragma unroll
                for (int u = 0; u < 8; ++u) {
                    int s = __shfl(myS, j + u);
                    wv[u] = __shfl(myW, j + u);
                    fv[u] = feat[(size_t)max(s, 0) * DD + lane];
                }
#pragma unroll
                for (int u = 0; u < 8; ++u) acc = fmaf(fv[u], wv[u], acc);
            }
            for (int j = 64; j < cnt; ++j) {
                int2 e = ed[(size_t)rc * STRIDE + j];
                int s = rk[e.x] - 1;
                acc = fmaf(feat[(size_t)max(s, 0) * DD + lane], __int_as_float(e.y), acc);
            }
        } else {
            for (int base = 0; base < NE; base += 64) {
                int d = rawdst[(size_t)g * NE + base + lane];
                int s = rawsrc[(size_t)g * NE + base + lane];
                float w = rawew[(size_t)g * NE + base + lane];
                unsigned long long mball = __ballot(d == n);
                while (mball) {
                    int i = __ffsll(mball) - 1; mball &= mball - 1;
                    int si = __shfl(s, i);
                    int srank = rk[si] - 1;
                    acc = fmaf(feat[(size_t)max(srank, 0) * DD + lane], __shfl(w, i), acc);
                }
            }
        }
        float neigh = acc / fmaxf((float)cnt, 1.f);
        fs[wid][lane] = fself;
        nsh[wid][lane] = neigh;
        float o = bv;
#pragma unroll
        for (int k4 = 0; k4 < 16; ++k4) {
            float4 ws4 = *(const float4*)&lws[lane][k4 * 4];
            float4 wn4 = *(const float4*)&lwn[lane][k4 * 4];
            float4 f  = *(const float4*)&fs[wid][k4 * 4];
            float4 nv = *(const float4*)&nsh[wid][k4 * 4];
            o = fmaf(ws4.x, f.x,  o);
            o = fmaf(ws4.y, f.y,  o);
            o = fmaf(ws4.z, f.z,  o);
            o = fmaf(ws4.w, f.w,  o);
            o = fmaf(wn4.x, nv.x, o);
            o = fmaf(wn4.y, nv.y, o);
            o = fmaf(wn4.z, nv.z, o);
            o = fmaf(wn4.w, nv.w, o);
        }
        sel[(((size_t)b * NG + g) * NL + l) * DD + lane] = o;  // no relu
    }
}

// ---------------------------------------------------------------- attention stack 1: (B*G) blocks over (L=50, D=64)
__global__ __launch_bounds__(256) void k_attn1(
    const float* __restrict__ sel, const float* __restrict__ Q,
    const float* __restrict__ K, const float* __restrict__ V,
    float* __restrict__ xsum)
{
    __shared__ __attribute__((aligned(16))) float x[NL * DD];
    __shared__ __attribute__((aligned(16))) float qp[NL * 68];
    __shared__ __attribute__((aligned(16))) float kk[NL * 68];
    const int tid = threadIdx.x;
    const int lane = tid & 63;
    const int wid = tid >> 6;
    const int bg = blockIdx.x;
    const float* xin = sel + (size_t)bg * NL * DD;
    for (int i = tid; i < NL * DD; i += 256) x[i] = xin[i];
    __syncthreads();

    for (int layer = 0; layer < NCL; ++layer) {
        const float* Qb = Q + (size_t)layer * DD * DD;
        const float* Kb = K + (size_t)layer * DD * DD;
        const float* Vb = V + (size_t)layer * DD * DD;
        float wrow[DD];
#pragma unroll
        for (int k4 = 0; k4 < 16; ++k4) {
            float4 a = *(const float4*)(Qb + (size_t)lane * DD + 4 * k4);
            wrow[4 * k4 + 0] = a.x; wrow[4 * k4 + 1] = a.y; wrow[4 * k4 + 2] = a.z; wrow[4 * k4 + 3] = a.w;
        }
        for (int l = wid; l < NL; l += 4) {
            float acc = 0.f;
#pragma unroll
            for (int k4 = 0; k4 < 16; ++k4) {
                float4 xv = *(const float4*)&x[l * DD + 4 * k4];
                acc = fmaf(wrow[4 * k4 + 0], xv.x, acc);
                acc = fmaf(wrow[4 * k4 + 1], xv.y, acc);
                acc = fmaf(wrow[4 * k4 + 2], xv.z, acc);
                acc = fmaf(wrow[4 * k4 + 3], xv.w, acc);
            }
            qp[l * 68 + lane] = acc;
        }
#pragma unroll
        for (int k4 = 0; k4 < 16; ++k4) {
            float4 a = *(const float4*)(Kb + (size_t)lane * DD + 4 * k4);
            wrow[4 * k4 + 0] = a.x; wrow[4 * k4 + 1] = a.y; wrow[4 * k4 + 2] = a.z; wrow[4 * k4 + 3] = a.w;
        }
        for (int l = wid; l < NL; l += 4) {
            float acc = 0.f;
#pragma unroll
            for (int k4 = 0; k4 < 16; ++k4) {
                float4 xv = *(const float4*)&x[l * DD + 4 * k4];
                acc = fmaf(wrow[4 * k4 + 0], xv.x, acc);
                acc = fmaf(wrow[4 * k4 + 1], xv.y, acc);
                acc = fmaf(wrow[4 * k4 + 2], xv.z, acc);
                acc = fmaf(wrow[4 * k4 + 3], xv.w, acc);
            }
            kk[l * 68 + lane] = acc;
        }
        __syncthreads();
        for (int l = wid; l < NL; l += 4) {
            float s;
            if (lane < NL) {
                float acc = 0.f;
#pragma unroll
                for (int k4 = 0; k4 < 16; ++k4) {
                    float4 qv = *(const float4*)&qp[l * 68 + 4 * k4];
                    float4 kv = *(const float4*)&kk[lane * 68 + 4 * k4];
                    acc += qv.x * kv.x + qv.y * kv.y + qv.z * kv.z + qv.w * kv.w;
                }
                s = acc * 0.125f;
            } else {
                s = -INFINITY;
            }
            float mx = s;
#pragma unroll
            for (int m = 32; m >= 1; m >>= 1) mx = fmaxf(mx, __shfl_xor(mx, m));
            float pe = __expf(s - mx);
            float sm = pe;
#pragma unroll
            for (int m = 32; m >= 1; m >>= 1) sm += __shfl_xor(sm, m);
            qp[l * 68 + lane] = pe / sm;
        }
        __syncthreads();
        for (int l = wid; l < NL; l += 4) {
            float acc = 0.f;
            for (int m = 0; m < NL; ++m)
                acc = fmaf(qp[l * 68 + m], x[m * DD + lane], acc);
            kk[l * 68 + lane] = acc;
        }
        __syncthreads();
#pragma unroll
        for (int k4 = 0; k4 < 16; ++k4) {
            float4 a = *(const float4*)(Vb + (size_t)lane * DD + 4 * k4);
            wrow[4 * k4 + 0] = a.x; wrow[4 * k4 + 1] = a.y; wrow[4 * k4 + 2] = a.z; wrow[4 * k4 + 3] = a.w;
        }
        for (int l = wid; l < NL; l += 4) {
            float acc = 0.f;
#pragma unroll
            for (int k4 = 0; k4 < 16; ++k4) {
                float4 yv = *(const float4*)&kk[l * 68 + 4 * k4];
                acc = fmaf(wrow[4 * k4 + 0], yv.x, acc);
                acc = fmaf(wrow[4 * k4 + 1], yv.y, acc);
                acc = fmaf(wrow[4 * k4 + 2], yv.z, acc);
                acc = fmaf(wrow[4 * k4 + 3], yv.w, acc);
            }
            x[l * DD + lane] = acc;
        }
        __syncthreads();
    }
    if (wid == 0) {
        float acc = 0.f;
        for (int l = 0; l < NL; ++l) acc += x[l * DD + lane];
        xsum[(size_t)bg * DD + lane] = acc;
    }
}

// ---------------------------------------------------------------- attention stack 2: B blocks over (G=4, D=64)
__global__ __launch_bounds__(64) void k_attn2(
    const float* __restrict__ xin, const float* __restrict__ Q,
    const float* __restrict__ K, const float* __restrict__ V,
    float* __restrict__ out)
{
    __shared__ __attribute__((aligned(16))) float x[NG * DD];
    const int j = threadIdx.x;
    const int b = blockIdx.x;
    for (int i = j; i < NG * DD; i += 64) x[i] = xin[(size_t)b * NG * DD + i];
    __syncthreads();
    float o[NG];
    for (int layer = 0; layer < NCL; ++layer) {
        float wrow[DD];
        float q4[NG], k4v[NG], v4[NG];
        const float* Qb = Q + (size_t)layer * DD * DD + (size_t)j * DD;
        const float* Kb = K + (size_t)layer * DD * DD + (size_t)j * DD;
        const float* Vb = V + (size_t)layer * DD * DD + (size_t)j * DD;
#pragma unroll
        for (int k4 = 0; k4 < 16; ++k4) {
            float4 a = *(const float4*)(Qb + 4 * k4);
            wrow[4 * k4 + 0] = a.x; wrow[4 * k4 + 1] = a.y; wrow[4 * k4 + 2] = a.z; wrow[4 * k4 + 3] = a.w;
        }
#pragma unroll
        for (int g = 0; g < NG; ++g) {
            float acc = 0.f;
#pragma unroll
            for (int k4 = 0; k4 < 16; ++k4) {
                float4 xv = *(const float4*)&x[g * DD + 4 * k4];
                acc = fmaf(wrow[4 * k4 + 0], xv.x, acc);
                acc = fmaf(wrow[4 * k4 + 1], xv.y, acc);
                acc = fmaf(wrow[4 * k4 + 2], xv.z, acc);
                acc = fmaf(wrow[4 * k4 + 3], xv.w, acc);
            }
            q4[g] = acc;
        }
#pragma unroll
        for (int k4 = 0; k4 < 16; ++k4) {
            float4 a = *(const float4*)(Kb + 4 * k4);
            wrow[4 * k4 + 0] = a.x; wrow[4 * k4 + 1] = a.y; wrow[4 * k4 + 2] = a.z; wrow[4 * k4 + 3] = a.w;
        }
#pragma unroll
        for (int g = 0; g < NG; ++g) {
            float acc = 0.f;
#pragma unroll
            for (int k4 = 0; k4 < 16; ++k4) {
                float4 xv = *(const float4*)&x[g * DD + 4 * k4];
                acc = fmaf(wrow[4 * k4 + 0], xv.x, acc);
                acc = fmaf(wrow[4 * k4 + 1], xv.y, acc);
                acc = fmaf(wrow[4 * k4 + 2], xv.z, acc);
                acc = fmaf(wrow[4 * k4 + 3], xv.w, acc);
            }
            k4v[g] = acc;
        }
#pragma unroll
        for (int k4 = 0; k4 < 16; ++k4) {
            float4 a = *(const float4*)(Vb + 4 * k4);
            wrow[4 * k4 + 0] = a.x; wrow[4 * k4 + 1] = a.y; wrow[4 * k4 + 2] = a.z; wrow[4 * k4 + 3] = a.w;
        }
#pragma unroll
        for (int g = 0; g < NG; ++g) {
            float acc = 0.f;
#pragma unroll
            for (int k4 = 0; k4 < 16; ++k4) {
                float4 xv = *(const float4*)&x[g * DD + 4 * k4];
                acc = fmaf(wrow[4 * k4 + 0], xv.x, acc);
                acc = fmaf(wrow[4 * k4 + 1], xv.y, acc);
                acc = fmaf(wrow[4 * k4 + 2], xv.z, acc);
                acc = fmaf(wrow[4 * k4 + 3], xv.w, acc);
            }
            v4[g] = acc;
        }
        float p[NG][NG];
#pragma unroll
        for (int l = 0; l < NG; ++l) {
#pragma unroll
            for (int m = 0; m < NG; ++m) {
                float t = q4[l] * k4v[m];
#pragma unroll
                for (int mk = 32; mk >= 1; mk >>= 1) t += __shfl_xor(t, mk);
                p[l][m] = t * 0.125f;
            }
        }
#pragma unroll
        for (int l = 0; l < NG; ++l) {
            float mx = fmaxf(fmaxf(p[l][0], p[l][1]), fmaxf(p[l][2], p[l][3]));
            float e0 = __expf(p[l][0] - mx), e1 = __expf(p[l][1] - mx);
            float e2 = __expf(p[l][2] - mx), e3 = __expf(p[l][3] - mx);
            float inv = 1.f / (e0 + e1 + e2 + e3);
            o[l] = (e0 * v4[0] + e1 * v4[1] + e2 * v4[2] + e3 * v4[3]) * inv;
        }
        __syncthreads();
#pragma unroll
        for (int l = 0; l < NG; ++l) x[l * DD + j] = o[l];
        __syncthreads();
    }
    out[(size_t)b * DD + j] = o[0] + o[1] + o[2] + o[3];
}

// ---------------------------------------------------------------- host
extern "C" void kernel_launch(void* const* d_in, const int* in_sizes, int n_in,
                              void* d_out, int out_size, void* d_ws, size_t ws_size,
                              hipStream_t stream)
{
    const int*   src  = (const int*)  d_in[0];
    const int*   dst  = (const int*)  d_in[1];
    const float* ew   = (const float*)d_in[2];
    const float* emb  = (const float*)d_in[3];
    const float* Ws1  = (const float*)d_in[4];
    const float* Wn1  = (const float*)d_in[5];
    const float* b1   = (const float*)d_in[6];
    const float* Ws2  = (const float*)d_in[7];
    const float* Wn2  = (const float*)d_in[8];
    const float* b2   = (const float*)d_in[9];
    const float* Q1   = (const float*)d_in[10];
    const float* K1   = (const float*)d_in[11];
    const float* V1   = (const float*)d_in[12];
    const float* Q2   = (const float*)d_in[13];
    const float* K2   = (const float*)d_in[14];
    const float* V2   = (const float*)d_in[15];
    const int*   cand = (const int*)  d_in[16];
    float* out = (float*)d_out;

    auto padded = [](size_t b) { return (b + 255) & ~(size_t)255; };
    auto need = [&](int GG) -> size_t {
        size_t s = 0;
        s += padded((size_t)GG * ROWCAP * STRIDE * 8);  // fixed-stride edges
        s += padded((size_t)GG * ROWCAP * DD * 4);      // h (rank rows)
        s += padded((size_t)GG * ROWCAP * 4);           // cur (counts)
        s += padded((size_t)NB_ * NG * NL * DD * 4);    // sel
        s += padded((size_t)NB_ * NG * DD * 4);         // xsum
        s += padded((size_t)GG * NN * 4) * 4;           // cbm, mark, list, rank
        s += padded((size_t)GG * 64 * 4) * 2;           // partc, nlist
        s += padded((size_t)GG * 2 * DD * DD * 4);      // transposed weights
        return s;
    };
    const int GG = (ws_size >= need(4)) ? 4 : 1;

    char* p = (char*)d_ws;
    auto alloc = [&](size_t b) -> void* { void* r = (void*)p; p += padded(b); return r; };
    int2*  edf  = (int2*) alloc((size_t)GG * ROWCAP * STRIDE * 8);
    float* hb   = (float*)alloc((size_t)GG * ROWCAP * DD * 4);
    int*   cur  = (int*)  alloc((size_t)GG * ROWCAP * 4);
    float* sel  = (float*)alloc((size_t)NB_ * NG * NL * DD * 4);
    float* xsum = (float*)alloc((size_t)NB_ * NG * DD * 4);
    int*   cbm  = (int*)  alloc((size_t)GG * NN * 4);
    int*   mark = (int*)  alloc((size_t)GG * NN * 4);
    int*   list = (int*)  alloc((size_t)GG * NN * 4);
    int*   rank = (int*)  alloc((size_t)GG * NN * 4);
    int*   prtc = (int*)  alloc((size_t)GG * 64 * 4);
    int*   nlst = (int*)  alloc((size_t)GG * 64 * 4);
    float* wt   = (float*)alloc((size_t)GG * 2 * DD * DD * 4);

    const int QB = (NE / 4 + 255) / 256;
    const int CB = (NB_ * NL + 255) / 256;
    for (int g0 = 0; g0 < NG; g0 += GG) {
        hipMemsetAsync(cbm, 0, (size_t)GG * NN * 4, stream);
        hipMemsetAsync(mark, 0, (size_t)GG * NN * 4, stream);
        hipMemsetAsync(cur, 0, (size_t)GG * ROWCAP * 4, stream);
        k_wt      <<<dim3(16, GG), 256, 0, stream>>>(Ws1, Wn1, wt, g0);
        k_candmark<<<dim3(CB, GG), 256, 0, stream>>>(cand, cbm, mark, g0);
        k_mark2   <<<dim3(QB, GG), 256, 0, stream>>>(src, dst, cbm, mark, g0);
        k_cscan1  <<<dim3(SCAN_NB, GG), 256, 0, stream>>>(mark, prtc);
        k_cscan3  <<<dim3(SCAN_NB, GG), 256, 0, stream>>>(mark, prtc, list, rank, nlst);
        k_scatter3<<<dim3(QB, GG), 256, 0, stream>>>(src, dst, ew, rank, cur, edf, g0);
        k_conv_full<<<dim3(1600, GG), 256, 0, stream>>>(emb, edf, cur, wt, b1, hb, list, nlst,
                                                        src, dst, ew, g0);
        k_conv_cand<<<dim3((NB_ * NL) / 4, GG), 256, 0, stream>>>(hb, edf, cur, rank, Ws2, Wn2, b2,
                                                                  cand, src, dst, ew, sel, g0);
    }
    k_attn1<<<NB_ * NG, 256, 0, stream>>>(sel, Q1, K1, V1, xsum);
    k_attn2<<<NB_, 64, 0, stream>>>(xsum, Q2, K2, V2, out);
}

// Round 13
// 339.829 us; speedup vs baseline: 1.0452x; 1.0452x over previous
//
#include <hip/hip_runtime.h>
#include <cstdint>
#include <cstddef>
#include <cmath>

#define NN   100000   // nodes per graph
#define NE   1600000  // edges per graph
#define DD   64       // feature dim
#define NG   4        // graphs
#define NB_  32       // batch
#define NL   50       // candidate list length
#define NCL  2        // attention layers per stack
#define SCAN_NB 49    // ceil(NN/2048)
#define STRIDE 80     // edge slots per marked row (Poisson(16): P(deg>80)~1e-34; exact fallback exists)
#define ROWCAP 32768  // max marked rows stored per graph (actual ~27k)
#define WPAD 68

// ---------------------------------------------------------------- fused: transpose layer-1 weights + mark candidates
// bx < 16: wt transpose (4096 threads for 64x64); bx >= 16: candidate marking
__global__ __launch_bounds__(256) void k_prep(const float* __restrict__ Ws,
                                              const float* __restrict__ Wn,
                                              float* __restrict__ wt,
                                              const int* __restrict__ cand,
                                              int* __restrict__ candbm,
                                              int* __restrict__ mark, int g0) {
    const int gy = blockIdx.y;
    const int g = g0 + gy;
    if (blockIdx.x < 16) {
        int i = blockIdx.x * 256 + threadIdx.x;
        float* o = wt + (size_t)gy * 2 * DD * DD;
        int r = i >> 6, k = i & 63;
        o[k * DD + r] = Ws[(size_t)g * DD * DD + r * DD + k];
        o[DD * DD + k * DD + r] = Wn[(size_t)g * DD * DD + r * DD + k];
    } else {
        int t = (blockIdx.x - 16) * 256 + threadIdx.x;
        if (t < NB_ * NL) {
            int b = t / NL, l = t - b * NL;
            int n = cand[((size_t)b * NG + g) * NL + l];
            candbm[(size_t)gy * NN + n] = 1;
            mark[(size_t)gy * NN + n] = 1;
        }
    }
}

// stream edges: mark sources feeding candidates
__global__ __launch_bounds__(256) void k_mark2(const int* __restrict__ src,
                                               const int* __restrict__ dst,
                                               const int* __restrict__ candbm,
                                               int* __restrict__ mark, int g0) {
    const int gy = blockIdx.y;
    const int g = g0 + gy;
    int q = blockIdx.x * 256 + threadIdx.x;
    if (q < NE / 4) {
        int4 dv = ((const int4*)(dst + (size_t)g * NE))[q];
        int4 sv = ((const int4*)(src + (size_t)g * NE))[q];
        const int* cb = candbm + (size_t)gy * NN;
        int* mk = mark + (size_t)gy * NN;
        if (cb[dv.x]) mk[sv.x] = 1;
        if (cb[dv.y]) mk[sv.y] = 1;
        if (cb[dv.z]) mk[sv.z] = 1;
        if (cb[dv.w]) mk[sv.w] = 1;
    }
}

// ---------------------------------------------------------------- compact marked -> list + rank
__global__ __launch_bounds__(256) void k_cscan1(const int* __restrict__ mark,
                                                int* __restrict__ partc) {
    const int gy = blockIdx.y;
    const int* m = mark + (size_t)gy * NN;
    __shared__ int sh[256];
    const int tid = threadIdx.x;
    int base = blockIdx.x * 2048 + tid * 8;
    int s = 0;
    for (int i = 0; i < 8; ++i) { int idx = base + i; if (idx < NN) s += m[idx]; }
    sh[tid] = s; __syncthreads();
    for (int off = 128; off > 0; off >>= 1) {
        if (tid < off) sh[tid] += sh[tid + off];
        __syncthreads();
    }
    if (tid == 0) partc[gy * 64 + blockIdx.x] = sh[0];
}

__global__ __launch_bounds__(256) void k_cscan3(const int* __restrict__ mark,
                                                const int* __restrict__ partc,
                                                int* __restrict__ list,
                                                int* __restrict__ rank,
                                                int* __restrict__ nlist) {
    const int gy = blockIdx.y;
    const int* m = mark + (size_t)gy * NN;
    int* li = list + (size_t)gy * NN;
    int* rk = rank + (size_t)gy * NN;
    __shared__ int sh[256];
    __shared__ int sbase;
    const int tid = threadIdx.x;
    if (tid == 0) {
        int b = 0;
        for (int i = 0; i < blockIdx.x; ++i) b += partc[gy * 64 + i];
        sbase = b;
    }
    int base = blockIdx.x * 2048 + tid * 8;
    int vals[8];
    int s = 0;
    for (int i = 0; i < 8; ++i) {
        int idx = base + i;
        int v = (idx < NN) ? m[idx] : 0;
        vals[i] = v; s += v;
    }
    sh[tid] = s; __syncthreads();
    for (int off = 1; off < 256; off <<= 1) {
        int t = (tid >= off) ? sh[tid - off] : 0;
        __syncthreads();
        sh[tid] += t;
        __syncthreads();
    }
    int excl = sh[tid] - s;
    int run = sbase + excl;
    for (int i = 0; i < 8; ++i) {
        int idx = base + i;
        if (idx < NN) {
            if (vals[i]) { li[run] = idx; rk[idx] = run + 1; ++run; }
            else rk[idx] = 0;
        }
    }
    if (blockIdx.x == SCAN_NB - 1 && tid == 255) nlist[gy] = sbase + sh[255];
}

// ---------------------------------------------------------------- fixed-stride scatter: slot base = rank*STRIDE, atomic cursor per row
__global__ __launch_bounds__(256) void k_scatter3(const int* __restrict__ src,
                                                  const int* __restrict__ dst,
                                                  const float* __restrict__ ew,
                                                  const int* __restrict__ rank,
                                                  int* __restrict__ cur,
                                                  int2* __restrict__ edf, int g0) {
    const int gy = blockIdx.y;
    const int g = g0 + gy;
    int q = blockIdx.x * 256 + threadIdx.x;
    if (q < NE / 4) {
        int4   dv = ((const int4*)(dst + (size_t)g * NE))[q];
        int4   sv = ((const int4*)(src + (size_t)g * NE))[q];
        float4 wv = ((const float4*)(ew + (size_t)g * NE))[q];
        const int* rk = rank + (size_t)gy * NN;
        int* cu = cur + (size_t)gy * ROWCAP;
        int2* ef = edf + (size_t)gy * ROWCAP * STRIDE;
        int r0 = rk[dv.x] - 1;
        if (r0 >= 0) { int p = atomicAdd(&cu[r0], 1); if (p < STRIDE) ef[(size_t)r0 * STRIDE + p] = make_int2(sv.x, __float_as_int(wv.x)); }
        int r1 = rk[dv.y] - 1;
        if (r1 >= 0) { int p = atomicAdd(&cu[r1], 1); if (p < STRIDE) ef[(size_t)r1 * STRIDE + p] = make_int2(sv.y, __float_as_int(wv.y)); }
        int r2 = rk[dv.z] - 1;
        if (r2 >= 0) { int p = atomicAdd(&cu[r2], 1); if (p < STRIDE) ef[(size_t)r2 * STRIDE + p] = make_int2(sv.z, __float_as_int(wv.z)); }
        int r3 = rk[dv.w] - 1;
        if (r3 >= 0) { int p = atomicAdd(&cu[r3], 1); if (p < STRIDE) ef[(size_t)r3 * STRIDE + p] = make_int2(sv.w, __float_as_int(wv.w)); }
    }
}

// ---------------------------------------------------------------- fused SAGE conv (layer 1, relu): 8-row tiles, phase-split
// (round-11 measured-best form: 126us, VGPR 60, 16KB LDS, occupancy 40%)
__global__ __launch_bounds__(256) void k_conv_full(
    const float* __restrict__ emb, const int2* __restrict__ edf,
    const int* __restrict__ cur, const float* __restrict__ wt,
    const float* __restrict__ bias, float* __restrict__ outh,
    const int* __restrict__ list, const int* __restrict__ nlist,
    const int* __restrict__ rawsrc, const int* __restrict__ rawdst,
    const float* __restrict__ rawew, int g0)
{
    const int gy = blockIdx.y;
    const int g = g0 + gy;
    const float* feat = emb + (size_t)g * NN * DD;
    const int2* ed = edf + (size_t)gy * ROWCAP * STRIDE;
    const int* cu = cur + (size_t)gy * ROWCAP;
    const int* li = list + (size_t)gy * NN;
    const float* wsT = wt + (size_t)gy * 2 * DD * DD;
    const float* wnT = wsT + DD * DD;
    float* og = outh + (size_t)gy * ROWCAP * DD;
    const int lane = threadIdx.x & 63;
    const int wid = threadIdx.x >> 6;

    __shared__ __attribute__((aligned(16))) float fs[4][8][DD];
    __shared__ __attribute__((aligned(16))) float ns[4][8][DD];

    const float bv = bias[(size_t)g * DD + lane];
    const int nl = min(nlist[gy], ROWCAP);
    const int wglob = blockIdx.x * 4 + wid;
    const int wstep = gridDim.x * 4;
    for (int tb = wglob * 8; tb < nl; tb += wstep * 8) {
        const int nrows = min(8, nl - tb);
        int nL = 0, cL = 0;
        if (lane < nrows) { nL = li[tb + lane]; cL = cu[tb + lane]; }
        // prefetch edge records for all rows (independent loads, in flight together)
        int2 rec[8];
#pragma unroll
        for (int r = 0; r < 8; ++r) {
            rec[r] = make_int2(0, 0);
            if (r < nrows) {
                int c = min(__shfl(cL, r), 64);
                if (lane < c) rec[r] = ed[(size_t)(tb + r) * STRIDE + lane];
            }
        }
        // ---- phase 1: gathers for all rows
        for (int r = 0; r < nrows; ++r) {
            const int n = __shfl(nL, r);
            const int cnt = __shfl(cL, r);
            fs[wid][r][lane] = feat[(size_t)n * DD + lane];
            float acc = 0.f;
            if (cnt <= STRIDE) {
                const int c64 = min(cnt, 64);
                int   myS;
                float myW;
                switch (r) {  // static-index the prefetched record
                    case 0: myS = rec[0].x; myW = __int_as_float(rec[0].y); break;
                    case 1: myS = rec[1].x; myW = __int_as_float(rec[1].y); break;
                    case 2: myS = rec[2].x; myW = __int_as_float(rec[2].y); break;
                    case 3: myS = rec[3].x; myW = __int_as_float(rec[3].y); break;
                    case 4: myS = rec[4].x; myW = __int_as_float(rec[4].y); break;
                    case 5: myS = rec[5].x; myW = __int_as_float(rec[5].y); break;
                    case 6: myS = rec[6].x; myW = __int_as_float(rec[6].y); break;
                    default: myS = rec[7].x; myW = __int_as_float(rec[7].y); break;
                }
                for (int j = 0; j < c64; j += 8) {
                    float fv[8], wv[8];
#pragma unroll
                    for (int u = 0; u < 8; ++u) {
                        int s = __shfl(myS, j + u);
                        wv[u] = __shfl(myW, j + u);
                        fv[u] = feat[(size_t)s * DD + lane];
                    }
#pragma unroll
                    for (int u = 0; u < 8; ++u) acc = fmaf(fv[u], wv[u], acc);
                }
                for (int j = 64; j < cnt; ++j) {           // deg 65..80 (cold)
                    int2 e = ed[(size_t)(tb + r) * STRIDE + j];
                    acc = fmaf(feat[(size_t)e.x * DD + lane], __int_as_float(e.y), acc);
                }
            } else {
                // exact fallback (never triggers for Poisson(16)): stream raw edges
                for (int base = 0; base < NE; base += 64) {
                    int d = rawdst[(size_t)g * NE + base + lane];
                    int s = rawsrc[(size_t)g * NE + base + lane];
                    float w = rawew[(size_t)g * NE + base + lane];
                    unsigned long long mball = __ballot(d == n);
                    while (mball) {
                        int i = __ffsll(mball) - 1; mball &= mball - 1;
                        acc = fmaf(feat[(size_t)__shfl(s, i) * DD + lane], __shfl(w, i), acc);
                    }
                }
            }
            ns[wid][r][lane] = acc / fmaxf((float)cnt, 1.f);
        }
        // ---- phase 2: register-blocked matvec for 8 rows
        float o[8];
#pragma unroll
        for (int r = 0; r < 8; ++r) o[r] = bv;
        for (int k4 = 0; k4 < 16; ++k4) {
            float ws0 = wsT[(4 * k4 + 0) * DD + lane];
            float ws1 = wsT[(4 * k4 + 1) * DD + lane];
            float ws2 = wsT[(4 * k4 + 2) * DD + lane];
            float ws3 = wsT[(4 * k4 + 3) * DD + lane];
            float wn0 = wnT[(4 * k4 + 0) * DD + lane];
            float wn1 = wnT[(4 * k4 + 1) * DD + lane];
            float wn2 = wnT[(4 * k4 + 2) * DD + lane];
            float wn3 = wnT[(4 * k4 + 3) * DD + lane];
#pragma unroll
            for (int r = 0; r < 8; ++r) {
                float4 f  = *(const float4*)&fs[wid][r][4 * k4];   // broadcast read
                float4 nv = *(const float4*)&ns[wid][r][4 * k4];   // broadcast read
                o[r] = fmaf(ws0, f.x,  o[r]);
                o[r] = fmaf(ws1, f.y,  o[r]);
                o[r] = fmaf(ws2, f.z,  o[r]);
                o[r] = fmaf(ws3, f.w,  o[r]);
                o[r] = fmaf(wn0, nv.x, o[r]);
                o[r] = fmaf(wn1, nv.y, o[r]);
                o[r] = fmaf(wn2, nv.z, o[r]);
                o[r] = fmaf(wn3, nv.w, o[r]);
            }
        }
#pragma unroll
        for (int r = 0; r < 8; ++r)
            if (r < nrows) og[(size_t)(tb + r) * DD + lane] = fmaxf(o[r], 0.f);
    }
}

// ---------------------------------------------------------------- fused SAGE conv at candidates (layer 2), h indexed via rank
__global__ __launch_bounds__(256) void k_conv_cand(
    const float* __restrict__ hfeat, const int2* __restrict__ edf,
    const int* __restrict__ cur, const int* __restrict__ rank,
    const float* __restrict__ Wsf, const float* __restrict__ Wng,
    const float* __restrict__ bias, const int* __restrict__ cand,
    const int* __restrict__ rawsrc, const int* __restrict__ rawdst,
    const float* __restrict__ rawew,
    float* __restrict__ sel, int g0)
{
    const int gy = blockIdx.y;
    const int g = g0 + gy;
    const float* feat = hfeat + (size_t)gy * ROWCAP * DD;  // rank-indexed
    const int2* ed = edf + (size_t)gy * ROWCAP * STRIDE;
    const int* cu = cur + (size_t)gy * ROWCAP;
    const int* rk = rank + (size_t)gy * NN;
    const int lane = threadIdx.x & 63;
    const int wid = threadIdx.x >> 6;

    __shared__ __attribute__((aligned(16))) float lws[DD][WPAD];
    __shared__ __attribute__((aligned(16))) float lwn[DD][WPAD];
    __shared__ __attribute__((aligned(16))) float fs[4][DD];
    __shared__ __attribute__((aligned(16))) float nsh[4][DD];

    for (int i = threadIdx.x; i < DD * 16; i += 256) {
        int row = i >> 4, blk = i & 15;
        *(float4*)&lws[row][blk * 4] = *(const float4*)(Wsf + (size_t)g * DD * DD + (size_t)row * DD + blk * 4);
        *(float4*)&lwn[row][blk * 4] = *(const float4*)(Wng + (size_t)g * DD * DD + (size_t)row * DD + blk * 4);
    }
    __syncthreads();
    const float bv = bias[(size_t)g * DD + lane];

    int t = blockIdx.x * 4 + wid;  // 0..1599
    if (t < NB_ * NL) {
        int b = t / NL;
        int l = t - b * NL;
        int n = cand[((size_t)b * NG + g) * NL + l];
        const int rc = rk[n] - 1;             // candidate is marked
        const int cnt = cu[rc];
        const float fself = feat[(size_t)rc * DD + lane];
        float acc = 0.f;
        if (cnt <= STRIDE) {
            const int c64 = min(cnt, 64);
            int myS = 0; float myW = 0.f;
            if (lane < c64) {
                int2 e = ed[(size_t)rc * STRIDE + lane];
                myS = rk[e.x] - 1;            // sources of candidates are marked
                myW = __int_as_float(e.y);
            }
            for (int j = 0; j < c64; j += 8) {
                float fv[8], wv[8];
#pragma unroll
                for (int u = 0; u < 8; ++u) {
                    int s = __shfl(myS, j + u);
                    wv[u] = __shfl(myW, j + u);
                    fv[u] = feat[(size_t)max(s, 0) * DD + lane];
                }
#pragma unroll
                for (int u = 0; u < 8; ++u) acc = fmaf(fv[u], wv[u], acc);
            }
            for (int j = 64; j < cnt; ++j) {
                int2 e = ed[(size_t)rc * STRIDE + j];
                int s = rk[e.x] - 1;
                acc = fmaf(feat[(size_t)max(s, 0) * DD + lane], __int_as_float(e.y), acc);
            }
        } else {
            for (int base = 0; base < NE; base += 64) {
                int d = rawdst[(size_t)g * NE + base + lane];
                int s = rawsrc[(size_t)g * NE + base + lane];
                float w = rawew[(size_t)g * NE + base + lane];
                unsigned long long mball = __ballot(d == n);
                while (mball) {
                    int i = __ffsll(mball) - 1; mball &= mball - 1;
                    int si = __shfl(s, i);
                    int srank = rk[si] - 1;
                    acc = fmaf(feat[(size_t)max(srank, 0) * DD + lane], __shfl(w, i), acc);
                }
            }
        }
        float neigh = acc / fmaxf((float)cnt, 1.f);
        fs[wid][lane] = fself;
        nsh[wid][lane] = neigh;
        float o = bv;
#pragma unroll
        for (int k4 = 0; k4 < 16; ++k4) {
            float4 ws4 = *(const float4*)&lws[lane][k4 * 4];
            float4 wn4 = *(const float4*)&lwn[lane][k4 * 4];
            float4 f  = *(const float4*)&fs[wid][k4 * 4];
            float4 nv = *(const float4*)&nsh[wid][k4 * 4];
            o = fmaf(ws4.x, f.x,  o);
            o = fmaf(ws4.y, f.y,  o);
            o = fmaf(ws4.z, f.z,  o);
            o = fmaf(ws4.w, f.w,  o);
            o = fmaf(wn4.x, nv.x, o);
            o = fmaf(wn4.y, nv.y, o);
            o = fmaf(wn4.z, nv.z, o);
            o = fmaf(wn4.w, nv.w, o);
        }
        sel[(((size_t)b * NG + g) * NL + l) * DD + lane] = o;  // no relu
    }
}

// ---------------------------------------------------------------- attention stack 1: (B*G) blocks over (L=50, D=64)
__global__ __launch_bounds__(256) void k_attn1(
    const float* __restrict__ sel, const float* __restrict__ Q,
    const float* __restrict__ K, const float* __restrict__ V,
    float* __restrict__ xsum)
{
    __shared__ __attribute__((aligned(16))) float x[NL * DD];
    __shared__ __attribute__((aligned(16))) float qp[NL * 68];
    __shared__ __attribute__((aligned(16))) float kk[NL * 68];
    const int tid = threadIdx.x;
    const int lane = tid & 63;
    const int wid = tid >> 6;
    const int bg = blockIdx.x;
    const float* xin = sel + (size_t)bg * NL * DD;
    for (int i = tid; i < NL * DD; i += 256) x[i] = xin[i];
    __syncthreads();

    for (int layer = 0; layer < NCL; ++layer) {
        const float* Qb = Q + (size_t)layer * DD * DD;
        const float* Kb = K + (size_t)layer * DD * DD;
        const float* Vb = V + (size_t)layer * DD * DD;
        float wrow[DD];
#pragma unroll
        for (int k4 = 0; k4 < 16; ++k4) {
            float4 a = *(const float4*)(Qb + (size_t)lane * DD + 4 * k4);
            wrow[4 * k4 + 0] = a.x; wrow[4 * k4 + 1] = a.y; wrow[4 * k4 + 2] = a.z; wrow[4 * k4 + 3] = a.w;
        }
        for (int l = wid; l < NL; l += 4) {
            float acc = 0.f;
#pragma unroll
            for (int k4 = 0; k4 < 16; ++k4) {
                float4 xv = *(const float4*)&x[l * DD + 4 * k4];
                acc = fmaf(wrow[4 * k4 + 0], xv.x, acc);
                acc = fmaf(wrow[4 * k4 + 1], xv.y, acc);
                acc = fmaf(wrow[4 * k4 + 2], xv.z, acc);
                acc = fmaf(wrow[4 * k4 + 3], xv.w, acc);
            }
            qp[l * 68 + lane] = acc;
        }
#pragma unroll
        for (int k4 = 0; k4 < 16; ++k4) {
            float4 a = *(const float4*)(Kb + (size_t)lane * DD + 4 * k4);
            wrow[4 * k4 + 0] = a.x; wrow[4 * k4 + 1] = a.y; wrow[4 * k4 + 2] = a.z; wrow[4 * k4 + 3] = a.w;
        }
        for (int l = wid; l < NL; l += 4) {
            float acc = 0.f;
#pragma unroll
            for (int k4 = 0; k4 < 16; ++k4) {
                float4 xv = *(const float4*)&x[l * DD + 4 * k4];
                acc = fmaf(wrow[4 * k4 + 0], xv.x, acc);
                acc = fmaf(wrow[4 * k4 + 1], xv.y, acc);
                acc = fmaf(wrow[4 * k4 + 2], xv.z, acc);
                acc = fmaf(wrow[4 * k4 + 3], xv.w, acc);
            }
            kk[l * 68 + lane] = acc;
        }
        __syncthreads();
        for (int l = wid; l < NL; l += 4) {
            float s;
            if (lane < NL) {
                float acc = 0.f;
#pragma unroll
                for (int k4 = 0; k4 < 16; ++k4) {
                    float4 qv = *(const float4*)&qp[l * 68 + 4 * k4];
                    float4 kv = *(const float4*)&kk[lane * 68 + 4 * k4];
                    acc += qv.x * kv.x + qv.y * kv.y + qv.z * kv.z + qv.w * kv.w;
                }
                s = acc * 0.125f;
            } else {
                s = -INFINITY;
            }
            float mx = s;
#pragma unroll
            for (int m = 32; m >= 1; m >>= 1) mx = fmaxf(mx, __shfl_xor(mx, m));
            float pe = __expf(s - mx);
            float sm = pe;
#pragma unroll
            for (int m = 32; m >= 1; m >>= 1) sm += __shfl_xor(sm, m);
            qp[l * 68 + lane] = pe / sm;
        }
        __syncthreads();
        for (int l = wid; l < NL; l += 4) {
            float acc = 0.f;
            for (int m = 0; m < NL; ++m)
                acc = fmaf(qp[l * 68 + m], x[m * DD + lane], acc);
            kk[l * 68 + lane] = acc;
        }
        __syncthreads();
#pragma unroll
        for (int k4 = 0; k4 < 16; ++k4) {
            float4 a = *(const float4*)(Vb + (size_t)lane * DD + 4 * k4);
            wrow[4 * k4 + 0] = a.x; wrow[4 * k4 + 1] = a.y; wrow[4 * k4 + 2] = a.z; wrow[4 * k4 + 3] = a.w;
        }
        for (int l = wid; l < NL; l += 4) {
            float acc = 0.f;
#pragma unroll
            for (int k4 = 0; k4 < 16; ++k4) {
                float4 yv = *(const float4*)&kk[l * 68 + 4 * k4];
                acc = fmaf(wrow[4 * k4 + 0], yv.x, acc);
                acc = fmaf(wrow[4 * k4 + 1], yv.y, acc);
                acc = fmaf(wrow[4 * k4 + 2], yv.z, acc);
                acc = fmaf(wrow[4 * k4 + 3], yv.w, acc);
            }
            x[l * DD + lane] = acc;
        }
        __syncthreads();
    }
    if (wid == 0) {
        float acc = 0.f;
        for (int l = 0; l < NL; ++l) acc += x[l * DD + lane];
        xsum[(size_t)bg * DD + lane] = acc;
    }
}

// ---------------------------------------------------------------- attention stack 2: B blocks over (G=4, D=64)
__global__ __launch_bounds__(64) void k_attn2(
    const float* __restrict__ xin, const float* __restrict__ Q,
    const float* __restrict__ K, const float* __restrict__ V,
    float* __restrict__ out)
{
    __shared__ __attribute__((aligned(16))) float x[NG * DD];
    const int j = threadIdx.x;
    const int b = blockIdx.x;
    for (int i = j; i < NG * DD; i += 64) x[i] = xin[(size_t)b * NG * DD + i];
    __syncthreads();
    float o[NG];
    for (int layer = 0; layer < NCL; ++layer) {
        float wrow[DD];
        float q4[NG], k4v[NG], v4[NG];
        const float* Qb = Q + (size_t)layer * DD * DD + (size_t)j * DD;
        const float* Kb = K + (size_t)layer * DD * DD + (size_t)j * DD;
        const float* Vb = V + (size_t)layer * DD * DD + (size_t)j * DD;
#pragma unroll
        for (int k4 = 0; k4 < 16; ++k4) {
            float4 a = *(const float4*)(Qb + 4 * k4);
            wrow[4 * k4 + 0] = a.x; wrow[4 * k4 + 1] = a.y; wrow[4 * k4 + 2] = a.z; wrow[4 * k4 + 3] = a.w;
        }
#pragma unroll
        for (int g = 0; g < NG; ++g) {
            float acc = 0.f;
#pragma unroll
            for (int k4 = 0; k4 < 16; ++k4) {
                float4 xv = *(const float4*)&x[g * DD + 4 * k4];
                acc = fmaf(wrow[4 * k4 + 0], xv.x, acc);
                acc = fmaf(wrow[4 * k4 + 1], xv.y, acc);
                acc = fmaf(wrow[4 * k4 + 2], xv.z, acc);
                acc = fmaf(wrow[4 * k4 + 3], xv.w, acc);
            }
            q4[g] = acc;
        }
#pragma unroll
        for (int k4 = 0; k4 < 16; ++k4) {
            float4 a = *(const float4*)(Kb + 4 * k4);
            wrow[4 * k4 + 0] = a.x; wrow[4 * k4 + 1] = a.y; wrow[4 * k4 + 2] = a.z; wrow[4 * k4 + 3] = a.w;
        }
#pragma unroll
        for (int g = 0; g < NG; ++g) {
            float acc = 0.f;
#pragma unroll
            for (int k4 = 0; k4 < 16; ++k4) {
                float4 xv = *(const float4*)&x[g * DD + 4 * k4];
                acc = fmaf(wrow[4 * k4 + 0], xv.x, acc);
                acc = fmaf(wrow[4 * k4 + 1], xv.y, acc);
                acc = fmaf(wrow[4 * k4 + 2], xv.z, acc);
                acc = fmaf(wrow[4 * k4 + 3], xv.w, acc);
            }
            k4v[g] = acc;
        }
#pragma unroll
        for (int k4 = 0; k4 < 16; ++k4) {
            float4 a = *(const float4*)(Vb + 4 * k4);
            wrow[4 * k4 + 0] = a.x; wrow[4 * k4 + 1] = a.y; wrow[4 * k4 + 2] = a.z; wrow[4 * k4 + 3] = a.w;
        }
#pragma unroll
        for (int g = 0; g < NG; ++g) {
            float acc = 0.f;
#pragma unroll
            for (int k4 = 0; k4 < 16; ++k4) {
                float4 xv = *(const float4*)&x[g * DD + 4 * k4];
                acc = fmaf(wrow[4 * k4 + 0], xv.x, acc);
                acc = fmaf(wrow[4 * k4 + 1], xv.y, acc);
                acc = fmaf(wrow[4 * k4 + 2], xv.z, acc);
                acc = fmaf(wrow[4 * k4 + 3], xv.w, acc);
            }
            v4[g] = acc;
        }
        float p[NG][NG];
#pragma unroll
        for (int l = 0; l < NG; ++l) {
#pragma unroll
            for (int m = 0; m < NG; ++m) {
                float t = q4[l] * k4v[m];
#pragma unroll
                for (int mk = 32; mk >= 1; mk >>= 1) t += __shfl_xor(t, mk);
                p[l][m] = t * 0.125f;
            }
        }
#pragma unroll
        for (int l = 0; l < NG; ++l) {
            float mx = fmaxf(fmaxf(p[l][0], p[l][1]), fmaxf(p[l][2], p[l][3]));
            float e0 = __expf(p[l][0] - mx), e1 = __expf(p[l][1] - mx);
            float e2 = __expf(p[l][2] - mx), e3 = __expf(p[l][3] - mx);
            float inv = 1.f / (e0 + e1 + e2 + e3);
            o[l] = (e0 * v4[0] + e1 * v4[1] + e2 * v4[2] + e3 * v4[3]) * inv;
        }
        __syncthreads();
#pragma unroll
        for (int l = 0; l < NG; ++l) x[l * DD + j] = o[l];
        __syncthreads();
    }
    out[(size_t)b * DD + j] = o[0] + o[1] + o[2] + o[3];
}

// ---------------------------------------------------------------- host
extern "C" void kernel_launch(void* const* d_in, const int* in_sizes, int n_in,
                              void* d_out, int out_size, void* d_ws, size_t ws_size,
                              hipStream_t stream)
{
    const int*   src  = (const int*)  d_in[0];
    const int*   dst  = (const int*)  d_in[1];
    const float* ew   = (const float*)d_in[2];
    const float* emb  = (const float*)d_in[3];
    const float* Ws1  = (const float*)d_in[4];
    const float* Wn1  = (const float*)d_in[5];
    const float* b1   = (const float*)d_in[6];
    const float* Ws2  = (const float*)d_in[7];
    const float* Wn2  = (const float*)d_in[8];
    const float* b2   = (const float*)d_in[9];
    const float* Q1   = (const float*)d_in[10];
    const float* K1   = (const float*)d_in[11];
    const float* V1   = (const float*)d_in[12];
    const float* Q2   = (const float*)d_in[13];
    const float* K2   = (const float*)d_in[14];
    const float* V2   = (const float*)d_in[15];
    const int*   cand = (const int*)  d_in[16];
    float* out = (float*)d_out;

    auto padded = [](size_t b) { return (b + 255) & ~(size_t)255; };
    auto need = [&](int GG) -> size_t {
        size_t s = 0;
        s += padded((size_t)GG * ROWCAP * STRIDE * 8);  // fixed-stride edges
        s += padded((size_t)GG * ROWCAP * DD * 4);      // h (rank rows)
        s += padded((size_t)GG * NN * 4) * 2;           // cbm, mark (zeroed region start)
        s += padded((size_t)GG * ROWCAP * 4);           // cur (zeroed region end)
        s += padded((size_t)NB_ * NG * NL * DD * 4);    // sel
        s += padded((size_t)NB_ * NG * DD * 4);         // xsum
        s += padded((size_t)GG * NN * 4) * 2;           // list, rank
        s += padded((size_t)GG * 64 * 4) * 2;           // partc, nlist
        s += padded((size_t)GG * 2 * DD * DD * 4);      // transposed weights
        return s;
    };
    const int GG = (ws_size >= need(4)) ? 4 : 1;

    char* p = (char*)d_ws;
    auto alloc = [&](size_t b) -> void* { void* r = (void*)p; p += padded(b); return r; };
    int2*  edf  = (int2*) alloc((size_t)GG * ROWCAP * STRIDE * 8);
    float* hb   = (float*)alloc((size_t)GG * ROWCAP * DD * 4);
    // contiguous zeroed region: cbm | mark | cur -> one memset
    char*  zbase = p;
    int*   cbm  = (int*)  alloc((size_t)GG * NN * 4);
    int*   mark = (int*)  alloc((size_t)GG * NN * 4);
    int*   cur  = (int*)  alloc((size_t)GG * ROWCAP * 4);
    size_t znb  = (size_t)((char*)p - zbase);
    float* sel  = (float*)alloc((size_t)NB_ * NG * NL * DD * 4);
    float* xsum = (float*)alloc((size_t)NB_ * NG * DD * 4);
    int*   list = (int*)  alloc((size_t)GG * NN * 4);
    int*   rank = (int*)  alloc((size_t)GG * NN * 4);
    int*   prtc = (int*)  alloc((size_t)GG * 64 * 4);
    int*   nlst = (int*)  alloc((size_t)GG * 64 * 4);
    float* wt   = (float*)alloc((size_t)GG * 2 * DD * DD * 4);

    const int QB = (NE / 4 + 255) / 256;
    const int PB = 16 + (NB_ * NL + 255) / 256;  // wt blocks + candmark blocks
    for (int g0 = 0; g0 < NG; g0 += GG) {
        hipMemsetAsync(zbase, 0, znb, stream);
        k_prep    <<<dim3(PB, GG), 256, 0, stream>>>(Ws1, Wn1, wt, cand, cbm, mark, g0);
        k_mark2   <<<dim3(QB, GG), 256, 0, stream>>>(src, dst, cbm, mark, g0);
        k_cscan1  <<<dim3(SCAN_NB, GG), 256, 0, stream>>>(mark, prtc);
        k_cscan3  <<<dim3(SCAN_NB, GG), 256, 0, stream>>>(mark, prtc, list, rank, nlst);
        k_scatter3<<<dim3(QB, GG), 256, 0, stream>>>(src, dst, ew, rank, cur, edf, g0);
        k_conv_full<<<dim3(832, GG), 256, 0, stream>>>(emb, edf, cur, wt, b1, hb, list, nlst,
                                                       src, dst, ew, g0);
        k_conv_cand<<<dim3((NB_ * NL) / 4, GG), 256, 0, stream>>>(hb, edf, cur, rank, Ws2, Wn2, b2,
                                                                  cand, src, dst, ew, sel, g0);
    }
    k_attn1<<<NB_ * NG, 256, 0, stream>>>(sel, Q1, K1, V1, xsum);
    k_attn2<<<NB_, 64, 0, stream>>>(xsum, Q2, K2, V2, out);
}